// Round 16
// baseline (314.397 us; speedup 1.0000x reference)
//
#include <hip/hip_runtime.h>

#define NT 512
#define SCL (1.0f / 8192.0f)
#define PI_F 3.14159265358979323846f

// XOR swizzle: bijective involution on [0,4096); spreads power-of-2 strided
// trip accesses across banks. Applied at EVERY cb access.
__device__ __forceinline__ int P(int i) { return i ^ ((i >> 5) & 31); }

__device__ __forceinline__ float2 cmul(float2 a, float2 b) {
  return make_float2(a.x * b.x - a.y * b.y, a.x * b.y + a.y * b.x);
}
__device__ __forceinline__ float2 csqr(float2 a) {
  return make_float2(a.x * a.x - a.y * a.y, 2.f * a.x * a.y);
}
__device__ __forceinline__ float2 cadd(float2 a, float2 b) { return make_float2(a.x + b.x, a.y + b.y); }
__device__ __forceinline__ float2 csub(float2 a, float2 b) { return make_float2(a.x - b.x, a.y - b.y); }
__device__ __forceinline__ float2 cmuli (float2 a) { return make_float2(-a.y,  a.x); } // *(+i)
__device__ __forceinline__ float2 cmulmi(float2 a) { return make_float2( a.y, -a.x); } // *(-i)

constexpr float RT2 = 0.70710678118654752440f;
constexpr float CQ1 = 0.92387953251128675613f; // cos(pi/8)
constexpr float SQ1 = 0.38268343236508977173f; // sin(pi/8)
// C8[k] = W8^k = e^{-i pi k/4}
constexpr float C8x[4] = {1.f,  RT2, 0.f, -RT2};
constexpr float C8y[4] = {0.f, -RT2, -1.f, -RT2};
// C16[k] = W16^k = e^{-i pi k/8} — used as W_8192^{512k} in the fused loads
constexpr float C16x[8] = {1.f,  CQ1,  RT2,  SQ1, 0.f, -SQ1, -RT2, -CQ1};
constexpr float C16y[8] = {0.f, -SQ1, -RT2, -CQ1, -1.f, -CQ1, -RT2, -SQ1};

// In-register 8-point DIF, stages at register strides 4,2,1 (R7/R14-verified).
// Stage stride s uses twiddle b^{4/s} * W_{2s}^{j mod s}; UNIT means b == 1.
template<bool UNIT>
__device__ __forceinline__ void r8_fwd(float2* e, float2 b) {
  float2 b2, b4;
  if (!UNIT) { b2 = csqr(b); b4 = csqr(b2); }
  #pragma unroll
  for (int j = 0; j < 4; ++j) {
    float2 u = e[j], v = e[j + 4];
    float2 d = csub(u, v);
    e[j] = cadd(u, v);
    float2 c8 = make_float2(C8x[j], C8y[j]);
    if (UNIT) e[j + 4] = (j == 0) ? d : cmul(d, c8);
    else      e[j + 4] = cmul(d, (j == 0) ? b : cmul(b, c8));
  }
  #pragma unroll
  for (int o = 0; o < 8; o += 4) {
    #pragma unroll
    for (int j = 0; j < 2; ++j) {
      float2 u = e[o + j], v = e[o + j + 2];
      float2 d = csub(u, v);
      e[o + j] = cadd(u, v);
      if (UNIT) e[o + j + 2] = (j == 0) ? d : cmulmi(d);
      else      e[o + j + 2] = cmul(d, (j == 0) ? b2 : cmulmi(b2));
    }
  }
  #pragma unroll
  for (int o = 0; o < 8; o += 2) {
    float2 u = e[o], v = e[o + 1];
    float2 d = csub(u, v);
    e[o] = cadd(u, v);
    e[o + 1] = UNIT ? d : cmul(d, b4);
  }
}

// In-register 8-point DIT inverse, stages at strides 1,2,4. g = conj(beta).
template<bool UNIT>
__device__ __forceinline__ void r8_inv(float2* e, float2 g) {
  float2 g2, g4;
  if (!UNIT) { g2 = csqr(g); g4 = csqr(g2); }
  #pragma unroll
  for (int o = 0; o < 8; o += 2) {
    float2 t = UNIT ? e[o + 1] : cmul(e[o + 1], g4);
    float2 u = e[o];
    e[o] = cadd(u, t); e[o + 1] = csub(u, t);
  }
  #pragma unroll
  for (int o = 0; o < 8; o += 4) {
    #pragma unroll
    for (int j = 0; j < 2; ++j) {
      float2 v = e[o + j + 2];
      float2 t;
      if (UNIT) t = (j == 0) ? v : cmuli(v);
      else      t = cmul(v, (j == 0) ? g2 : cmuli(g2));
      float2 u = e[o + j];
      e[o + j] = cadd(u, t); e[o + j + 2] = csub(u, t);
    }
  }
  #pragma unroll
  for (int j = 0; j < 4; ++j) {
    float2 v = e[j + 4];
    float2 t;
    float2 c8c = make_float2(C8x[j], -C8y[j]);
    if (UNIT) t = (j == 0) ? v : cmul(v, c8c);
    else      t = cmul(v, (j == 0) ? g : cmul(g, c8c));
    float2 u = e[j];
    e[j] = cadd(u, t); e[j + 4] = csub(u, t);
  }
}

// 8x8 in-register transpose across 8 consecutive lanes (masks 1,2,4 butterfly).
// Entry: lane c (within its aligned 8-lane group) holds column c (reg r = row r)
// of the 8x8 block. Exit: lane c holds row c (reg r = col r). Self-inverse.
__device__ __forceinline__ void xpose8(float2* e, int tid) {
  #pragma unroll
  for (int m = 1; m < 8; m <<= 1) {
    #pragma unroll
    for (int r = 0; r < 8; ++r) {
      if ((r & m) == 0) {
        const bool hi = (tid & m) != 0;
        float2 a = hi ? e[r] : e[r | m];
        float2 b;
        b.x = __shfl_xor(a.x, m, 64);
        b.y = __shfl_xor(a.y, m, 64);
        if (hi) e[r] = b; else e[r | m] = b;
      }
    }
  }
}

// Single-group radix-8 trips on the 4096-entry buffer (one group per thread).
__device__ __forceinline__ void t8f(float2* cb, int base, int G, float2 b) {
  float2 e[8];
  #pragma unroll
  for (int j = 0; j < 8; ++j) e[j] = cb[P(base + G * j)];
  r8_fwd<false>(e, b);
  #pragma unroll
  for (int j = 0; j < 8; ++j) cb[P(base + G * j)] = e[j];
}

__device__ __forceinline__ void t8i(float2* cb, int base, int G, float2 g) {
  float2 e[8];
  #pragma unroll
  for (int j = 0; j < 8; ++j) e[j] = cb[P(base + G * j)];
  r8_inv<false>(e, g);
  #pragma unroll
  for (int j = 0; j < 8; ++j) cb[P(base + G * j)] = e[j];
}

// K2a: T-hat halves via the SAME radix-8 pipeline as fftconv (shared digit-
// reversal ordering). half0 input = t[n]; half1 = t[n]*W_8192^n. 4096 = 8^4.
// R16: trip C + MID-fwd fused via the 8x8 shuffle transpose; ThG written
// straight from registers (one fewer LDS round trip + barrier than R15).
// Scaled output written consumption-ordered: ThG[(2d+half)*4096 + tid + 512*j].
__global__ __launch_bounds__(NT)
void that8h(const float* __restrict__ tT, float2* __restrict__ ThG) {
  __shared__ float2 cb[4096];   // 32 KiB
  const int tid = threadIdx.x;
  const int d = blockIdx.x;
  const int half = blockIdx.y;

  const int baseB = ((tid >> 6) << 9) + (tid & 63);
  const int baseC = ((tid >> 3) << 6) + (tid & 7);

  float s0, c0; __sincosf(-PI_F * (float)tid / 2048.f, &s0, &c0);
  const float2 bA = make_float2(c0, s0);            // W_4096^tid
  float s1, c1; __sincosf(-PI_F * (float)(tid & 63) / 256.f, &s1, &c1);
  const float2 bB = make_float2(c1, s1);            // W_512^(tid&63)
  float s2, c2; __sincosf(-PI_F * (float)(tid & 7) / 32.f, &s2, &c2);
  const float2 bC = make_float2(c2, s2);            // W_64^(tid&7)
  float sw, cw; __sincosf(-PI_F * (float)tid / 4096.f, &sw, &cw);
  const float2 whi = make_float2(cw, sw);           // W_8192^tid

  const float* tp = tT + (size_t)d * 4096;
  {
    float2 e[8];
    #pragma unroll
    for (int j = 0; j < 8; ++j) {
      int n = tid + 512 * j;
      float tv = tp[n];
      if (half == 0) e[j] = make_float2(tv, 0.f);
      else {
        float2 w = (j == 0) ? whi : cmul(whi, make_float2(C16x[j], C16y[j])); // W_8192^n
        e[j] = make_float2(tv * w.x, tv * w.y);
      }
    }
    r8_fwd<false>(e, bA);
    #pragma unroll
    for (int j = 0; j < 8; ++j) cb[P(tid + 512 * j)] = e[j];
  }
  __syncthreads();
  t8f(cb, baseB, 64, bB);  __syncthreads();
  // C + MID-fwd fused: LDS read at G=8, fwd, transpose to row-major, unit fwd,
  // store scaled T-hat straight from registers.
  {
    float2 e[8];
    #pragma unroll
    for (int j = 0; j < 8; ++j) e[j] = cb[P(baseC + 8 * j)];
    r8_fwd<false>(e, bC);
    xpose8(e, tid);
    r8_fwd<true>(e, make_float2(1.f, 0.f));
    float2* thg = ThG + ((size_t)d * 2 + half) * 4096;
    #pragma unroll
    for (int j = 0; j < 8; ++j)
      thg[tid + 512 * j] = make_float2(e[j].x * SCL, e[j].y * SCL);
  }
}

// K2b: one WG per (channel d, pass). Half-split 8192-pt conv at the
// max-occupancy geometry (NT=512, radix-8, ~116 VGPR, 32 KiB LDS -> 2
// blocks/CU, 16 waves/CU). R16 change: trips C + MID + C' fused into ONE
// register phase via the 8x8 shuffle transpose (C-thread c holds column c of
// its 64-elem block; MID needs rows -> in-wave transpose, masks 1,2,4). Kills
// 2 LDS round trips + 2 barriers per half and the 4-way-conflicted G=1
// pattern entirely.
// Per half: A(fused load), B(G=64), [C+MID+C'](regs), B', A'(regs; lo keeps
// u[8], hi combines y = u + v*conj(W_8192^n) fused into the store).
__global__ __launch_bounds__(NT)
void fftconv(float* __restrict__ xT, const float2* __restrict__ ThG) {
  __shared__ float2 cb[4096];   // 32 KiB
  const int tid = threadIdx.x;
  const int d = blockIdx.x;
  const int pass = blockIdx.y;

  const int baseB = ((tid >> 6) << 9) + (tid & 63);
  const int baseC = ((tid >> 3) << 6) + (tid & 7);
  const float2 ONE = make_float2(1.f, 0.f);

  float s0, c0; __sincosf(-PI_F * (float)tid / 2048.f, &s0, &c0);
  const float2 bA = make_float2(c0, s0);            // W_4096^tid
  const float2 gA = make_float2(c0, -s0);
  float s1, c1; __sincosf(-PI_F * (float)(tid & 63) / 256.f, &s1, &c1);
  const float2 bB = make_float2(c1, s1);            // W_512^(tid&63)
  const float2 gB = make_float2(c1, -s1);
  float s2, c2; __sincosf(-PI_F * (float)(tid & 7) / 32.f, &s2, &c2);
  const float2 bC = make_float2(c2, s2);            // W_64^(tid&7)
  const float2 gC = make_float2(c2, -s2);
  float sw, cw; __sincosf(-PI_F * (float)tid / 4096.f, &sw, &cw);
  const float2 whi  = make_float2(cw, sw);          // W_8192^tid
  const float2 whic = make_float2(cw, -sw);

  float* r0 = xT + ((size_t)(2 * pass)     * 1024 + d) * 4096;
  float* r1 = xT + ((size_t)(2 * pass + 1) * 1024 + d) * 4096;
  const float2* thl = ThG + (size_t)d * 2 * 4096;
  const float2* thh = thl + 4096;

  float2 u[8];    // lo-half result, pinned through the hi half (16 VGPRs)
  float2 th[8];   // T-hat fragment (prefetched one phase early)

  // ---------------- lo half: input x (load fused into trip A) ----------------
  {
    float2 e[8];
    #pragma unroll
    for (int j = 0; j < 8; ++j) {
      int n = tid + 512 * j;
      e[j] = make_float2(r0[n], r1[n]);
    }
    r8_fwd<false>(e, bA);
    #pragma unroll
    for (int j = 0; j < 8; ++j) cb[P(tid + 512 * j)] = e[j];
  }
  __syncthreads();
  #pragma unroll
  for (int j = 0; j < 8; ++j) th[j] = thl[tid + 512 * j];  // overlaps trip B
  t8f(cb, baseB, 64, bB);  __syncthreads();
  // C + MID + C' fused (register phase, one LDS r/w at G=8)
  {
    float2 e[8];
    #pragma unroll
    for (int j = 0; j < 8; ++j) e[j] = cb[P(baseC + 8 * j)];
    r8_fwd<false>(e, bC);
    xpose8(e, tid);
    r8_fwd<true>(e, ONE);
    #pragma unroll
    for (int j = 0; j < 8; ++j) e[j] = cmul(e[j], th[j]);
    r8_inv<true>(e, ONE);
    xpose8(e, tid);
    r8_inv<false>(e, gC);
    #pragma unroll
    for (int j = 0; j < 8; ++j) cb[P(baseC + 8 * j)] = e[j];
  }
  __syncthreads();
  t8i(cb, baseB, 64, gB);  __syncthreads();
  #pragma unroll
  for (int j = 0; j < 8; ++j) u[j] = cb[P(tid + 512 * j)];
  r8_inv<false>(u, gA);     // u[k] = lo-half output at n = tid + 512k
  __syncthreads();          // cb reads done; hi half may overwrite

  // ------------- hi half: input x * W_8192^n (load fused into trip A) -------------
  {
    float2 e[8];
    #pragma unroll
    for (int j = 0; j < 8; ++j) {
      int n = tid + 512 * j;
      float2 xv = make_float2(r0[n], r1[n]);        // L2-hot re-read
      float2 w = (j == 0) ? whi : cmul(whi, make_float2(C16x[j], C16y[j])); // W_8192^n
      e[j] = cmul(xv, w);
    }
    r8_fwd<false>(e, bA);
    #pragma unroll
    for (int j = 0; j < 8; ++j) cb[P(tid + 512 * j)] = e[j];
  }
  __syncthreads();
  #pragma unroll
  for (int j = 0; j < 8; ++j) th[j] = thh[tid + 512 * j];  // overlaps trip B
  t8f(cb, baseB, 64, bB);  __syncthreads();
  {
    float2 e[8];
    #pragma unroll
    for (int j = 0; j < 8; ++j) e[j] = cb[P(baseC + 8 * j)];
    r8_fwd<false>(e, bC);
    xpose8(e, tid);
    r8_fwd<true>(e, ONE);
    #pragma unroll
    for (int j = 0; j < 8; ++j) e[j] = cmul(e[j], th[j]);
    r8_inv<true>(e, ONE);
    xpose8(e, tid);
    r8_inv<false>(e, gC);
    #pragma unroll
    for (int j = 0; j < 8; ++j) cb[P(baseC + 8 * j)] = e[j];
  }
  __syncthreads();
  t8i(cb, baseB, 64, gB);  __syncthreads();
  {
    float2 v[8];
    #pragma unroll
    for (int j = 0; j < 8; ++j) v[j] = cb[P(tid + 512 * j)];
    r8_inv<false>(v, gA);
    // final h=4096 inverse stage fused into the store: y = u + v*conj(W_8192^n)
    #pragma unroll
    for (int k = 0; k < 8; ++k) {
      float2 wc = (k == 0) ? whic : cmul(whic, make_float2(C16x[k], -C16y[k]));
      float2 t = cmul(v[k], wc);
      int n = tid + 512 * k;
      r0[n] = u[k].x + t.x;
      r1[n] = u[k].y + t.y;
    }
  }
}

// 64x64 tile transpose, 256 threads, float4 global I/O, padded LDS.
// At ~6.6 TB/s measured (R7) — HBM roofline; leave as is.
__global__ __launch_bounds__(256)
void transpose64(const float* __restrict__ src, float* __restrict__ dst, int R, int C) {
  __shared__ float tile[64][65];
  int t  = threadIdx.x;
  int c4 = t & 15;
  int r  = t >> 4;
  size_t slab = (size_t)blockIdx.z * (size_t)R * (size_t)C;
  const float* s = src + slab;
  float* dd = dst + slab;
  int col0 = blockIdx.x * 64, row0 = blockIdx.y * 64;
  #pragma unroll
  for (int k = 0; k < 4; ++k) {
    int rr = r + 16 * k;
    const float4 v = *(const float4*)(s + (size_t)(row0 + rr) * C + col0 + 4 * c4);
    tile[rr][4 * c4 + 0] = v.x;
    tile[rr][4 * c4 + 1] = v.y;
    tile[rr][4 * c4 + 2] = v.z;
    tile[rr][4 * c4 + 3] = v.w;
  }
  __syncthreads();
  #pragma unroll
  for (int k = 0; k < 4; ++k) {
    int cc = r + 16 * k;
    float4 w;
    w.x = tile[4 * c4 + 0][cc];
    w.y = tile[4 * c4 + 1][cc];
    w.z = tile[4 * c4 + 2][cc];
    w.w = tile[4 * c4 + 3][cc];
    *(float4*)(dd + (size_t)(col0 + cc) * R + row0 + 4 * c4) = w;
  }
}

extern "C" void kernel_launch(void* const* d_in, const int* in_sizes, int n_in,
                              void* d_out, int out_size, void* d_ws, size_t ws_size,
                              hipStream_t stream) {
  const float* x = (const float*)d_in[0];   // (4, 4096, 1024)
  const float* t = (const float*)d_in[1];   // (4096, 1024)
  float* out = (float*)d_out;               // (4, 4096, 1024) = 64 MB
  float* ws  = (float*)d_ws;
  float* xT  = ws;                                   // (4, 1024, 4096)  64 MB
  float* tT  = ws + (size_t)4 * 1024 * 4096;         // (1024, 4096)     16 MB
  // T-hat halves live in d_out (2048 * 4096 float2 = 64 MB exactly); consumed
  // by fftconv, then fully overwritten by the final transpose.
  float2* ThG = (float2*)d_out;

  transpose64<<<dim3(16, 64, 4), 256, 0, stream>>>(x, xT, 4096, 1024);
  transpose64<<<dim3(16, 64, 1), 256, 0, stream>>>(t, tT, 4096, 1024);

  that8h<<<dim3(1024, 2), NT, 0, stream>>>(tT, ThG);
  fftconv<<<dim3(1024, 2), NT, 0, stream>>>(xT, ThG);

  transpose64<<<dim3(64, 16, 4), 256, 0, stream>>>(xT, out, 1024, 4096);
}

// Round 17
// 152.519 us; speedup vs baseline: 2.0614x; 2.0614x over previous
//
#include <hip/hip_runtime.h>

#define NT 512
#define SCL (1.0f / 8192.0f)
#define PI_F 3.14159265358979323846f

// XOR swizzle: bijective involution on [0,4096); only bits 5-9 feed the XOR of
// bits 0-4, so it also preserves each 4096-half of an 8192 buffer:
// P(4096+i) = 4096+P(i). Applied at EVERY cb access.
__device__ __forceinline__ int P(int i) { return i ^ ((i >> 5) & 31); }

__device__ __forceinline__ float2 cmul(float2 a, float2 b) {
  return make_float2(a.x * b.x - a.y * b.y, a.x * b.y + a.y * b.x);
}
__device__ __forceinline__ float2 csqr(float2 a) {
  return make_float2(a.x * a.x - a.y * a.y, 2.f * a.x * a.y);
}
__device__ __forceinline__ float2 cadd(float2 a, float2 b) { return make_float2(a.x + b.x, a.y + b.y); }
__device__ __forceinline__ float2 csub(float2 a, float2 b) { return make_float2(a.x - b.x, a.y - b.y); }
__device__ __forceinline__ float2 cmuli (float2 a) { return make_float2(-a.y,  a.x); } // *(+i)
__device__ __forceinline__ float2 cmulmi(float2 a) { return make_float2( a.y, -a.x); } // *(-i)

constexpr float RT2 = 0.70710678118654752440f;
constexpr float CQ1 = 0.92387953251128675613f; // cos(pi/8)
constexpr float SQ1 = 0.38268343236508977173f; // sin(pi/8)
// C8[k] = W8^k = e^{-i pi k/4}
constexpr float C8x[4] = {1.f,  RT2, 0.f, -RT2};
constexpr float C8y[4] = {0.f, -RT2, -1.f, -RT2};
// C16[k] = W16^k = e^{-i pi k/8} — used as W_8192^{512k} in the fused loads
constexpr float C16x[8] = {1.f,  CQ1,  RT2,  SQ1, 0.f, -SQ1, -RT2, -CQ1};
constexpr float C16y[8] = {0.f, -SQ1, -RT2, -CQ1, -1.f, -CQ1, -RT2, -SQ1};

// In-register 8-point DIF, stages at register strides 4,2,1 (R7/R14-verified).
// Stage stride s uses twiddle b^{4/s} * W_{2s}^{j mod s}; UNIT means b == 1.
template<bool UNIT>
__device__ __forceinline__ void r8_fwd(float2* e, float2 b) {
  float2 b2, b4;
  if (!UNIT) { b2 = csqr(b); b4 = csqr(b2); }
  #pragma unroll
  for (int j = 0; j < 4; ++j) {
    float2 u = e[j], v = e[j + 4];
    float2 d = csub(u, v);
    e[j] = cadd(u, v);
    float2 c8 = make_float2(C8x[j], C8y[j]);
    if (UNIT) e[j + 4] = (j == 0) ? d : cmul(d, c8);
    else      e[j + 4] = cmul(d, (j == 0) ? b : cmul(b, c8));
  }
  #pragma unroll
  for (int o = 0; o < 8; o += 4) {
    #pragma unroll
    for (int j = 0; j < 2; ++j) {
      float2 u = e[o + j], v = e[o + j + 2];
      float2 d = csub(u, v);
      e[o + j] = cadd(u, v);
      if (UNIT) e[o + j + 2] = (j == 0) ? d : cmulmi(d);
      else      e[o + j + 2] = cmul(d, (j == 0) ? b2 : cmulmi(b2));
    }
  }
  #pragma unroll
  for (int o = 0; o < 8; o += 2) {
    float2 u = e[o], v = e[o + 1];
    float2 d = csub(u, v);
    e[o] = cadd(u, v);
    e[o + 1] = UNIT ? d : cmul(d, b4);
  }
}

// In-register 8-point DIT inverse, stages at strides 1,2,4. g = conj(beta).
template<bool UNIT>
__device__ __forceinline__ void r8_inv(float2* e, float2 g) {
  float2 g2, g4;
  if (!UNIT) { g2 = csqr(g); g4 = csqr(g2); }
  #pragma unroll
  for (int o = 0; o < 8; o += 2) {
    float2 t = UNIT ? e[o + 1] : cmul(e[o + 1], g4);
    float2 u = e[o];
    e[o] = cadd(u, t); e[o + 1] = csub(u, t);
  }
  #pragma unroll
  for (int o = 0; o < 8; o += 4) {
    #pragma unroll
    for (int j = 0; j < 2; ++j) {
      float2 v = e[o + j + 2];
      float2 t;
      if (UNIT) t = (j == 0) ? v : cmuli(v);
      else      t = cmul(v, (j == 0) ? g2 : cmuli(g2));
      float2 u = e[o + j];
      e[o + j] = cadd(u, t); e[o + j + 2] = csub(u, t);
    }
  }
  #pragma unroll
  for (int j = 0; j < 4; ++j) {
    float2 v = e[j + 4];
    float2 t;
    float2 c8c = make_float2(C8x[j], -C8y[j]);
    if (UNIT) t = (j == 0) ? v : cmul(v, c8c);
    else      t = cmul(v, (j == 0) ? g : cmul(g, c8c));
    float2 u = e[j];
    e[j] = cadd(u, t); e[j + 4] = csub(u, t);
  }
}

// Single-group radix-8 trips (one group per thread; base may include the
// 4096 half-offset — P preserves halves).
__device__ __forceinline__ void t8f(float2* cb, int base, int G, float2 b) {
  float2 e[8];
  #pragma unroll
  for (int j = 0; j < 8; ++j) e[j] = cb[P(base + G * j)];
  r8_fwd<false>(e, b);
  #pragma unroll
  for (int j = 0; j < 8; ++j) cb[P(base + G * j)] = e[j];
}

__device__ __forceinline__ void t8i(float2* cb, int base, int G, float2 g) {
  float2 e[8];
  #pragma unroll
  for (int j = 0; j < 8; ++j) e[j] = cb[P(base + G * j)];
  r8_inv<false>(e, g);
  #pragma unroll
  for (int j = 0; j < 8; ++j) cb[P(base + G * j)] = e[j];
}

// K2a: BOTH T-hat halves in one WG (R17: t loaded once; halves live in the
// two 4096-halves of cb; phases run both halves between barriers).
// half0 input = t[n]; half1 = t[n]*W_8192^n. 4096 = 8^4: A(fused load),
// B(G=64), C(G=8), MID-fwd + scaled store (consumption-ordered:
// ThG[(2d+half)*4096 + tid + 512*j]).
__global__ __launch_bounds__(NT)
void that8h(const float* __restrict__ tT, float2* __restrict__ ThG) {
  __shared__ float2 cb[8192];   // 64 KiB: lo half [0,4096), hi half [4096,8192)
  const int tid = threadIdx.x;
  const int d = blockIdx.x;

  const int baseB = ((tid >> 6) << 9) + (tid & 63);
  const int baseC = ((tid >> 3) << 6) + (tid & 7);

  float s0, c0; __sincosf(-PI_F * (float)tid / 2048.f, &s0, &c0);
  const float2 bA = make_float2(c0, s0);            // W_4096^tid
  float s1, c1; __sincosf(-PI_F * (float)(tid & 63) / 256.f, &s1, &c1);
  const float2 bB = make_float2(c1, s1);            // W_512^(tid&63)
  float s2, c2; __sincosf(-PI_F * (float)(tid & 7) / 32.f, &s2, &c2);
  const float2 bC = make_float2(c2, s2);            // W_64^(tid&7)
  float sw, cw; __sincosf(-PI_F * (float)tid / 4096.f, &sw, &cw);
  const float2 whi = make_float2(cw, sw);           // W_8192^tid

  const float* tp = tT + (size_t)d * 4096;
  {
    float2 tv[8];
    #pragma unroll
    for (int j = 0; j < 8; ++j) tv[j] = make_float2(tp[tid + 512 * j], 0.f);
    float2 e[8];
    #pragma unroll
    for (int j = 0; j < 8; ++j) e[j] = tv[j];
    r8_fwd<false>(e, bA);
    #pragma unroll
    for (int j = 0; j < 8; ++j) cb[P(tid + 512 * j)] = e[j];
    #pragma unroll
    for (int j = 0; j < 8; ++j) {
      float2 w = (j == 0) ? whi : cmul(whi, make_float2(C16x[j], C16y[j])); // W_8192^n
      e[j] = make_float2(tv[j].x * w.x, tv[j].x * w.y);
    }
    r8_fwd<false>(e, bA);
    #pragma unroll
    for (int j = 0; j < 8; ++j) cb[P(4096 + tid + 512 * j)] = e[j];
  }
  __syncthreads();
  t8f(cb, baseB, 64, bB);
  t8f(cb, 4096 + baseB, 64, bB);
  __syncthreads();
  t8f(cb, baseC, 8, bC);
  t8f(cb, 4096 + baseC, 8, bC);
  __syncthreads();
  float2* thg = ThG + (size_t)d * 2 * 4096;
  #pragma unroll 1
  for (int h = 0; h < 2; ++h) {
    float2 e[8];
    #pragma unroll
    for (int j = 0; j < 8; ++j) e[j] = cb[P(h * 4096 + tid * 8 + j)];
    r8_fwd<true>(e, make_float2(1.f, 0.f));
    #pragma unroll
    for (int j = 0; j < 8; ++j)
      thg[h * 4096 + tid + 512 * j] = make_float2(e[j].x * SCL, e[j].y * SCL);
  }
}

// K2b: one WG per (channel d, pass). R17: both independent 4096-pt half-convs
// run IN PARALLEL per phase in the two halves of cb[8192] — 7 barriers/pass
// (R15 ran the halves serially: ~13), and x is loaded ONCE (hi-half L2
// re-read deleted). LDS 64 KiB -> still 2 blocks/CU (128 of 160 KiB),
// 16 waves/CU; transients stay the R15 pattern (~116 VGPR, no spill).
// Phases: [load + A both], [B both], [C both], [MID both], [C' both],
// [B' both], [A' in regs + combine y = u + v*conj(W_8192^n) + store].
__global__ __launch_bounds__(NT)
void fftconv(float* __restrict__ xT, const float2* __restrict__ ThG) {
  __shared__ float2 cb[8192];   // 64 KiB: lo half [0,4096), hi half [4096,8192)
  const int tid = threadIdx.x;
  const int d = blockIdx.x;
  const int pass = blockIdx.y;

  const int baseB = ((tid >> 6) << 9) + (tid & 63);
  const int baseC = ((tid >> 3) << 6) + (tid & 7);
  const int baseM = tid << 3;
  const float2 ONE = make_float2(1.f, 0.f);

  float s0, c0; __sincosf(-PI_F * (float)tid / 2048.f, &s0, &c0);
  const float2 bA = make_float2(c0, s0);            // W_4096^tid
  const float2 gA = make_float2(c0, -s0);
  float s1, c1; __sincosf(-PI_F * (float)(tid & 63) / 256.f, &s1, &c1);
  const float2 bB = make_float2(c1, s1);            // W_512^(tid&63)
  const float2 gB = make_float2(c1, -s1);
  float s2, c2; __sincosf(-PI_F * (float)(tid & 7) / 32.f, &s2, &c2);
  const float2 bC = make_float2(c2, s2);            // W_64^(tid&7)
  const float2 gC = make_float2(c2, -s2);
  float sw, cw; __sincosf(-PI_F * (float)tid / 4096.f, &sw, &cw);
  const float2 whi  = make_float2(cw, sw);          // W_8192^tid
  const float2 whic = make_float2(cw, -sw);

  float* r0 = xT + ((size_t)(2 * pass)     * 1024 + d) * 4096;
  float* r1 = xT + ((size_t)(2 * pass + 1) * 1024 + d) * 4096;
  const float2* thl = ThG + (size_t)d * 2 * 4096;
  const float2* thh = thl + 4096;

  // ---- Phase 1: load x ONCE; trip A into both halves (lo: x, hi: x*W) ----
  {
    float2 xv[8];
    #pragma unroll
    for (int j = 0; j < 8; ++j) {
      int n = tid + 512 * j;
      xv[j] = make_float2(r0[n], r1[n]);
    }
    float2 e[8];
    #pragma unroll
    for (int j = 0; j < 8; ++j) e[j] = xv[j];
    r8_fwd<false>(e, bA);
    #pragma unroll
    for (int j = 0; j < 8; ++j) cb[P(tid + 512 * j)] = e[j];
    #pragma unroll
    for (int j = 0; j < 8; ++j) {
      float2 w = (j == 0) ? whi : cmul(whi, make_float2(C16x[j], C16y[j])); // W_8192^n
      e[j] = cmul(xv[j], w);
    }
    r8_fwd<false>(e, bA);
    #pragma unroll
    for (int j = 0; j < 8; ++j) cb[P(4096 + tid + 512 * j)] = e[j];
  }
  __syncthreads();

  // ---- Phase 2: T-hat prefetch (overlaps LDS work), then B on both halves ----
  float2 thL[8], thH[8];
  #pragma unroll
  for (int j = 0; j < 8; ++j) thL[j] = thl[tid + 512 * j];
  #pragma unroll
  for (int j = 0; j < 8; ++j) thH[j] = thh[tid + 512 * j];
  t8f(cb, baseB, 64, bB);
  t8f(cb, 4096 + baseB, 64, bB);
  __syncthreads();

  // ---- Phase 3: C on both halves ----
  t8f(cb, baseC, 8, bC);
  t8f(cb, 4096 + baseC, 8, bC);
  __syncthreads();

  // ---- Phase 4: MID on both halves (unit fwd + That* + unit inv) ----
  #pragma unroll 1
  for (int h = 0; h < 2; ++h) {
    float2 e[8];
    #pragma unroll
    for (int j = 0; j < 8; ++j) e[j] = cb[P(h * 4096 + baseM + j)];
    r8_fwd<true>(e, ONE);
    #pragma unroll
    for (int j = 0; j < 8; ++j) e[j] = cmul(e[j], h ? thH[j] : thL[j]);
    r8_inv<true>(e, ONE);
    #pragma unroll
    for (int j = 0; j < 8; ++j) cb[P(h * 4096 + baseM + j)] = e[j];
  }
  __syncthreads();

  // ---- Phase 5: C' on both halves ----
  t8i(cb, baseC, 8, gC);
  t8i(cb, 4096 + baseC, 8, gC);
  __syncthreads();

  // ---- Phase 6: B' on both halves ----
  t8i(cb, baseB, 64, gB);
  t8i(cb, 4096 + baseB, 64, gB);
  __syncthreads();

  // ---- Phase 7: A' in registers on both halves + combine + store ----
  {
    float2 u[8], v[8];
    #pragma unroll
    for (int j = 0; j < 8; ++j) u[j] = cb[P(tid + 512 * j)];
    r8_inv<false>(u, gA);
    #pragma unroll
    for (int j = 0; j < 8; ++j) v[j] = cb[P(4096 + tid + 512 * j)];
    r8_inv<false>(v, gA);
    // final h=4096 inverse stage fused into the store: y = u + v*conj(W_8192^n)
    #pragma unroll
    for (int k = 0; k < 8; ++k) {
      float2 wc = (k == 0) ? whic : cmul(whic, make_float2(C16x[k], -C16y[k]));
      float2 t = cmul(v[k], wc);
      int n = tid + 512 * k;
      r0[n] = u[k].x + t.x;
      r1[n] = u[k].y + t.y;
    }
  }
}

// 64x64 tile transpose, 256 threads, float4 global I/O, padded LDS.
// At ~6.6 TB/s measured (R7) — HBM roofline; leave as is.
__global__ __launch_bounds__(256)
void transpose64(const float* __restrict__ src, float* __restrict__ dst, int R, int C) {
  __shared__ float tile[64][65];
  int t  = threadIdx.x;
  int c4 = t & 15;
  int r  = t >> 4;
  size_t slab = (size_t)blockIdx.z * (size_t)R * (size_t)C;
  const float* s = src + slab;
  float* dd = dst + slab;
  int col0 = blockIdx.x * 64, row0 = blockIdx.y * 64;
  #pragma unroll
  for (int k = 0; k < 4; ++k) {
    int rr = r + 16 * k;
    const float4 v = *(const float4*)(s + (size_t)(row0 + rr) * C + col0 + 4 * c4);
    tile[rr][4 * c4 + 0] = v.x;
    tile[rr][4 * c4 + 1] = v.y;
    tile[rr][4 * c4 + 2] = v.z;
    tile[rr][4 * c4 + 3] = v.w;
  }
  __syncthreads();
  #pragma unroll
  for (int k = 0; k < 4; ++k) {
    int cc = r + 16 * k;
    float4 w;
    w.x = tile[4 * c4 + 0][cc];
    w.y = tile[4 * c4 + 1][cc];
    w.z = tile[4 * c4 + 2][cc];
    w.w = tile[4 * c4 + 3][cc];
    *(float4*)(dd + (size_t)(col0 + cc) * R + row0 + 4 * c4) = w;
  }
}

extern "C" void kernel_launch(void* const* d_in, const int* in_sizes, int n_in,
                              void* d_out, int out_size, void* d_ws, size_t ws_size,
                              hipStream_t stream) {
  const float* x = (const float*)d_in[0];   // (4, 4096, 1024)
  const float* t = (const float*)d_in[1];   // (4096, 1024)
  float* out = (float*)d_out;               // (4, 4096, 1024) = 64 MB
  float* ws  = (float*)d_ws;
  float* xT  = ws;                                   // (4, 1024, 4096)  64 MB
  float* tT  = ws + (size_t)4 * 1024 * 4096;         // (1024, 4096)     16 MB
  // T-hat halves live in d_out (2048 * 4096 float2 = 64 MB exactly); consumed
  // by fftconv, then fully overwritten by the final transpose.
  float2* ThG = (float2*)d_out;

  transpose64<<<dim3(16, 64, 4), 256, 0, stream>>>(x, xT, 4096, 1024);
  transpose64<<<dim3(16, 64, 1), 256, 0, stream>>>(t, tT, 4096, 1024);

  that8h<<<dim3(1024), NT, 0, stream>>>(tT, ThG);
  fftconv<<<dim3(1024, 2), NT, 0, stream>>>(xT, ThG);

  transpose64<<<dim3(64, 16, 4), 256, 0, stream>>>(xT, out, 1024, 4096);
}

// Round 18
// 147.914 us; speedup vs baseline: 2.1255x; 1.0311x over previous
//
#include <hip/hip_runtime.h>

#define NT 512
#define SCL (1.0f / 8192.0f)
#define PI_F 3.14159265358979323846f

// XOR swizzle: bijective involution on [0,4096) float4 indices.
__device__ __forceinline__ int P(int i) { return i ^ ((i >> 5) & 31); }

__device__ __forceinline__ float2 cmul(float2 a, float2 b) {
  return make_float2(a.x * b.x - a.y * b.y, a.x * b.y + a.y * b.x);
}
__device__ __forceinline__ float2 csqr(float2 a) {
  return make_float2(a.x * a.x - a.y * a.y, 2.f * a.x * a.y);
}
__device__ __forceinline__ float2 cadd(float2 a, float2 b) { return make_float2(a.x + b.x, a.y + b.y); }
__device__ __forceinline__ float2 csub(float2 a, float2 b) { return make_float2(a.x - b.x, a.y - b.y); }
__device__ __forceinline__ float2 cmuli (float2 a) { return make_float2(-a.y,  a.x); } // *(+i)
__device__ __forceinline__ float2 cmulmi(float2 a) { return make_float2( a.y, -a.x); } // *(-i)

constexpr float RT2 = 0.70710678118654752440f;
constexpr float CQ1 = 0.92387953251128675613f; // cos(pi/8)
constexpr float SQ1 = 0.38268343236508977173f; // sin(pi/8)
// C8[k] = W8^k = e^{-i pi k/4}
constexpr float C8x[4] = {1.f,  RT2, 0.f, -RT2};
constexpr float C8y[4] = {0.f, -RT2, -1.f, -RT2};
// C16[k] = W16^k = e^{-i pi k/8} — used as W_8192^{512k} in the fused loads
constexpr float C16x[8] = {1.f,  CQ1,  RT2,  SQ1, 0.f, -SQ1, -RT2, -CQ1};
constexpr float C16y[8] = {0.f, -SQ1, -RT2, -CQ1, -1.f, -CQ1, -RT2, -SQ1};

// In-register 8-point DIF, stages at register strides 4,2,1 (R7/R14-verified).
// Stage stride s uses twiddle b^{4/s} * W_{2s}^{j mod s}; UNIT means b == 1.
template<bool UNIT>
__device__ __forceinline__ void r8_fwd(float2* e, float2 b) {
  float2 b2, b4;
  if (!UNIT) { b2 = csqr(b); b4 = csqr(b2); }
  #pragma unroll
  for (int j = 0; j < 4; ++j) {
    float2 u = e[j], v = e[j + 4];
    float2 d = csub(u, v);
    e[j] = cadd(u, v);
    float2 c8 = make_float2(C8x[j], C8y[j]);
    if (UNIT) e[j + 4] = (j == 0) ? d : cmul(d, c8);
    else      e[j + 4] = cmul(d, (j == 0) ? b : cmul(b, c8));
  }
  #pragma unroll
  for (int o = 0; o < 8; o += 4) {
    #pragma unroll
    for (int j = 0; j < 2; ++j) {
      float2 u = e[o + j], v = e[o + j + 2];
      float2 d = csub(u, v);
      e[o + j] = cadd(u, v);
      if (UNIT) e[o + j + 2] = (j == 0) ? d : cmulmi(d);
      else      e[o + j + 2] = cmul(d, (j == 0) ? b2 : cmulmi(b2));
    }
  }
  #pragma unroll
  for (int o = 0; o < 8; o += 2) {
    float2 u = e[o], v = e[o + 1];
    float2 d = csub(u, v);
    e[o] = cadd(u, v);
    e[o + 1] = UNIT ? d : cmul(d, b4);
  }
}

// In-register 8-point DIT inverse, stages at strides 1,2,4. g = conj(beta).
template<bool UNIT>
__device__ __forceinline__ void r8_inv(float2* e, float2 g) {
  float2 g2, g4;
  if (!UNIT) { g2 = csqr(g); g4 = csqr(g2); }
  #pragma unroll
  for (int o = 0; o < 8; o += 2) {
    float2 t = UNIT ? e[o + 1] : cmul(e[o + 1], g4);
    float2 u = e[o];
    e[o] = cadd(u, t); e[o + 1] = csub(u, t);
  }
  #pragma unroll
  for (int o = 0; o < 8; o += 4) {
    #pragma unroll
    for (int j = 0; j < 2; ++j) {
      float2 v = e[o + j + 2];
      float2 t;
      if (UNIT) t = (j == 0) ? v : cmuli(v);
      else      t = cmul(v, (j == 0) ? g2 : cmuli(g2));
      float2 u = e[o + j];
      e[o + j] = cadd(u, t); e[o + j + 2] = csub(u, t);
    }
  }
  #pragma unroll
  for (int j = 0; j < 4; ++j) {
    float2 v = e[j + 4];
    float2 t;
    float2 c8c = make_float2(C8x[j], -C8y[j]);
    if (UNIT) t = (j == 0) ? v : cmul(v, c8c);
    else      t = cmul(v, (j == 0) ? g : cmul(g, c8c));
    float2 u = e[j];
    e[j] = cadd(u, t); e[j + 4] = csub(u, t);
  }
}

// Dual radix-8 trips on the float4-packed buffer: .xy = lo half, .zw = hi half.
// One ds_read_b128/ds_write_b128 per element pair (R18: halves LDS inst count
// and P() address VALU vs two float2 trips); twiddle regs shared across halves.
__device__ __forceinline__ void d8f(float4* cb, int base, int G, float2 b) {
  float2 lo[8], hi[8];
  #pragma unroll
  for (int j = 0; j < 8; ++j) {
    float4 q = cb[P(base + G * j)];
    lo[j] = make_float2(q.x, q.y);
    hi[j] = make_float2(q.z, q.w);
  }
  r8_fwd<false>(lo, b);
  r8_fwd<false>(hi, b);
  #pragma unroll
  for (int j = 0; j < 8; ++j)
    cb[P(base + G * j)] = make_float4(lo[j].x, lo[j].y, hi[j].x, hi[j].y);
}

__device__ __forceinline__ void d8i(float4* cb, int base, int G, float2 g) {
  float2 lo[8], hi[8];
  #pragma unroll
  for (int j = 0; j < 8; ++j) {
    float4 q = cb[P(base + G * j)];
    lo[j] = make_float2(q.x, q.y);
    hi[j] = make_float2(q.z, q.w);
  }
  r8_inv<false>(lo, g);
  r8_inv<false>(hi, g);
  #pragma unroll
  for (int j = 0; j < 8; ++j)
    cb[P(base + G * j)] = make_float4(lo[j].x, lo[j].y, hi[j].x, hi[j].y);
}

// K2a: both T-hat halves in one WG, float4-packed (R17 structure + R18 pack).
// half-lo input = t[n]; half-hi = t[n]*W_8192^n. 4096 = 8^4: A(fused load),
// B(G=64), C(G=8), MID-fwd + scaled store interleaved:
// ThG4[d*4096 + tid + 512*j] = {T-lo, T-hi} (fftconv reads it back as float4).
__global__ __launch_bounds__(NT)
void that8h(const float* __restrict__ tT, float4* __restrict__ ThG) {
  __shared__ float4 cb[4096];   // 64 KiB packed
  const int tid = threadIdx.x;
  const int d = blockIdx.x;

  const int baseB = ((tid >> 6) << 9) + (tid & 63);
  const int baseC = ((tid >> 3) << 6) + (tid & 7);

  float s0, c0; __sincosf(-PI_F * (float)tid / 2048.f, &s0, &c0);
  const float2 bA = make_float2(c0, s0);            // W_4096^tid
  float s1, c1; __sincosf(-PI_F * (float)(tid & 63) / 256.f, &s1, &c1);
  const float2 bB = make_float2(c1, s1);            // W_512^(tid&63)
  float s2, c2; __sincosf(-PI_F * (float)(tid & 7) / 32.f, &s2, &c2);
  const float2 bC = make_float2(c2, s2);            // W_64^(tid&7)
  float sw, cw; __sincosf(-PI_F * (float)tid / 4096.f, &sw, &cw);
  const float2 whi = make_float2(cw, sw);           // W_8192^tid

  const float* tp = tT + (size_t)d * 4096;
  {
    float tv[8];
    #pragma unroll
    for (int j = 0; j < 8; ++j) tv[j] = tp[tid + 512 * j];
    float2 lo[8], hi[8];
    #pragma unroll
    for (int j = 0; j < 8; ++j) {
      lo[j] = make_float2(tv[j], 0.f);
      float2 w = (j == 0) ? whi : cmul(whi, make_float2(C16x[j], C16y[j])); // W_8192^n
      hi[j] = make_float2(tv[j] * w.x, tv[j] * w.y);
    }
    r8_fwd<false>(lo, bA);
    r8_fwd<false>(hi, bA);
    #pragma unroll
    for (int j = 0; j < 8; ++j)
      cb[P(tid + 512 * j)] = make_float4(lo[j].x, lo[j].y, hi[j].x, hi[j].y);
  }
  __syncthreads();
  d8f(cb, baseB, 64, bB);  __syncthreads();
  d8f(cb, baseC, 8, bC);   __syncthreads();
  {
    float2 lo[8], hi[8];
    #pragma unroll
    for (int j = 0; j < 8; ++j) {
      float4 q = cb[P(tid * 8 + j)];
      lo[j] = make_float2(q.x, q.y);
      hi[j] = make_float2(q.z, q.w);
    }
    r8_fwd<true>(lo, make_float2(1.f, 0.f));
    r8_fwd<true>(hi, make_float2(1.f, 0.f));
    float4* thg = ThG + (size_t)d * 4096;
    #pragma unroll
    for (int j = 0; j < 8; ++j)
      thg[tid + 512 * j] = make_float4(lo[j].x * SCL, lo[j].y * SCL,
                                       hi[j].x * SCL, hi[j].y * SCL);
  }
}

// K2b: one WG per (channel d, pass). R17 parallel-halves structure + R18
// float4 pack: every phase touches one ds_*_b128 per pair instead of two
// b64s — LDS inst count and P() VALU halve at identical byte traffic.
// Phases: [load + A both], [B], [th prefetch + C], [MID], [C'], [B'],
// [A' in regs + combine y = u + v*conj(W_8192^n) + store].
__global__ __launch_bounds__(NT)
void fftconv(float* __restrict__ xT, const float4* __restrict__ ThG) {
  __shared__ float4 cb[4096];   // 64 KiB packed: .xy lo half, .zw hi half
  const int tid = threadIdx.x;
  const int d = blockIdx.x;
  const int pass = blockIdx.y;

  const int baseB = ((tid >> 6) << 9) + (tid & 63);
  const int baseC = ((tid >> 3) << 6) + (tid & 7);
  const float2 ONE = make_float2(1.f, 0.f);

  float s0, c0; __sincosf(-PI_F * (float)tid / 2048.f, &s0, &c0);
  const float2 bA = make_float2(c0, s0);            // W_4096^tid
  const float2 gA = make_float2(c0, -s0);
  float s1, c1; __sincosf(-PI_F * (float)(tid & 63) / 256.f, &s1, &c1);
  const float2 bB = make_float2(c1, s1);            // W_512^(tid&63)
  const float2 gB = make_float2(c1, -s1);
  float s2, c2; __sincosf(-PI_F * (float)(tid & 7) / 32.f, &s2, &c2);
  const float2 bC = make_float2(c2, s2);            // W_64^(tid&7)
  const float2 gC = make_float2(c2, -s2);
  float sw, cw; __sincosf(-PI_F * (float)tid / 4096.f, &sw, &cw);
  const float2 whi  = make_float2(cw, sw);          // W_8192^tid
  const float2 whic = make_float2(cw, -sw);

  float* r0 = xT + ((size_t)(2 * pass)     * 1024 + d) * 4096;
  float* r1 = xT + ((size_t)(2 * pass + 1) * 1024 + d) * 4096;
  const float4* thg = ThG + (size_t)d * 4096;

  // ---- Phase 1: load x ONCE; trip A on both halves (lo: x, hi: x*W) ----
  {
    float2 xv[8], m[8];
    #pragma unroll
    for (int j = 0; j < 8; ++j) {
      int n = tid + 512 * j;
      xv[j] = make_float2(r0[n], r1[n]);
    }
    #pragma unroll
    for (int j = 0; j < 8; ++j) {
      float2 w = (j == 0) ? whi : cmul(whi, make_float2(C16x[j], C16y[j])); // W_8192^n
      m[j] = cmul(xv[j], w);
    }
    r8_fwd<false>(xv, bA);   // xv -> lo-half trip A output
    r8_fwd<false>(m, bA);    // m  -> hi-half trip A output
    #pragma unroll
    for (int j = 0; j < 8; ++j)
      cb[P(tid + 512 * j)] = make_float4(xv[j].x, xv[j].y, m[j].x, m[j].y);
  }
  __syncthreads();

  // ---- Phase 2: B on both halves ----
  d8f(cb, baseB, 64, bB);
  __syncthreads();

  // ---- Phase 3: T-hat prefetch (overlaps trip C), then C on both halves ----
  float4 thq[8];
  #pragma unroll
  for (int j = 0; j < 8; ++j) thq[j] = thg[tid + 512 * j];
  d8f(cb, baseC, 8, bC);
  __syncthreads();

  // ---- Phase 4: MID on both halves (unit fwd + That* + unit inv) ----
  {
    float2 lo[8], hi[8];
    #pragma unroll
    for (int j = 0; j < 8; ++j) {
      float4 q = cb[P(tid * 8 + j)];
      lo[j] = make_float2(q.x, q.y);
      hi[j] = make_float2(q.z, q.w);
    }
    r8_fwd<true>(lo, ONE);
    r8_fwd<true>(hi, ONE);
    #pragma unroll
    for (int j = 0; j < 8; ++j) {
      lo[j] = cmul(lo[j], make_float2(thq[j].x, thq[j].y));
      hi[j] = cmul(hi[j], make_float2(thq[j].z, thq[j].w));
    }
    r8_inv<true>(lo, ONE);
    r8_inv<true>(hi, ONE);
    #pragma unroll
    for (int j = 0; j < 8; ++j)
      cb[P(tid * 8 + j)] = make_float4(lo[j].x, lo[j].y, hi[j].x, hi[j].y);
  }
  __syncthreads();

  // ---- Phase 5: C' on both halves ----
  d8i(cb, baseC, 8, gC);
  __syncthreads();

  // ---- Phase 6: B' on both halves ----
  d8i(cb, baseB, 64, gB);
  __syncthreads();

  // ---- Phase 7: A' in registers on both halves + combine + store ----
  {
    float2 u[8], v[8];
    #pragma unroll
    for (int j = 0; j < 8; ++j) {
      float4 q = cb[P(tid + 512 * j)];
      u[j] = make_float2(q.x, q.y);
      v[j] = make_float2(q.z, q.w);
    }
    r8_inv<false>(u, gA);
    r8_inv<false>(v, gA);
    // final h=4096 inverse stage fused into the store: y = u + v*conj(W_8192^n)
    #pragma unroll
    for (int k = 0; k < 8; ++k) {
      float2 wc = (k == 0) ? whic : cmul(whic, make_float2(C16x[k], -C16y[k]));
      float2 t = cmul(v[k], wc);
      int n = tid + 512 * k;
      r0[n] = u[k].x + t.x;
      r1[n] = u[k].y + t.y;
    }
  }
}

// 64x64 tile transpose, 256 threads, float4 global I/O, padded LDS.
// At ~6.6 TB/s measured (R7) — HBM roofline; leave as is.
__global__ __launch_bounds__(256)
void transpose64(const float* __restrict__ src, float* __restrict__ dst, int R, int C) {
  __shared__ float tile[64][65];
  int t  = threadIdx.x;
  int c4 = t & 15;
  int r  = t >> 4;
  size_t slab = (size_t)blockIdx.z * (size_t)R * (size_t)C;
  const float* s = src + slab;
  float* dd = dst + slab;
  int col0 = blockIdx.x * 64, row0 = blockIdx.y * 64;
  #pragma unroll
  for (int k = 0; k < 4; ++k) {
    int rr = r + 16 * k;
    const float4 v = *(const float4*)(s + (size_t)(row0 + rr) * C + col0 + 4 * c4);
    tile[rr][4 * c4 + 0] = v.x;
    tile[rr][4 * c4 + 1] = v.y;
    tile[rr][4 * c4 + 2] = v.z;
    tile[rr][4 * c4 + 3] = v.w;
  }
  __syncthreads();
  #pragma unroll
  for (int k = 0; k < 4; ++k) {
    int cc = r + 16 * k;
    float4 w;
    w.x = tile[4 * c4 + 0][cc];
    w.y = tile[4 * c4 + 1][cc];
    w.z = tile[4 * c4 + 2][cc];
    w.w = tile[4 * c4 + 3][cc];
    *(float4*)(dd + (size_t)(col0 + cc) * R + row0 + 4 * c4) = w;
  }
}

extern "C" void kernel_launch(void* const* d_in, const int* in_sizes, int n_in,
                              void* d_out, int out_size, void* d_ws, size_t ws_size,
                              hipStream_t stream) {
  const float* x = (const float*)d_in[0];   // (4, 4096, 1024)
  const float* t = (const float*)d_in[1];   // (4096, 1024)
  float* out = (float*)d_out;               // (4, 4096, 1024) = 64 MB
  float* ws  = (float*)d_ws;
  float* xT  = ws;                                   // (4, 1024, 4096)  64 MB
  float* tT  = ws + (size_t)4 * 1024 * 4096;         // (1024, 4096)     16 MB
  // T-hat (interleaved lo/hi float4) lives in d_out: 1024*4096*16B = 64 MB
  // exactly; consumed by fftconv, then fully overwritten by the final transpose.
  float4* ThG = (float4*)d_out;

  transpose64<<<dim3(16, 64, 4), 256, 0, stream>>>(x, xT, 4096, 1024);
  transpose64<<<dim3(16, 64, 1), 256, 0, stream>>>(t, tT, 4096, 1024);

  that8h<<<dim3(1024), NT, 0, stream>>>(tT, ThG);
  fftconv<<<dim3(1024, 2), NT, 0, stream>>>(xT, ThG);

  transpose64<<<dim3(64, 16, 4), 256, 0, stream>>>(xT, out, 1024, 4096);
}